// Round 1
// baseline (68.748 us; speedup 1.0000x reference)
//
#include <hip/hip_runtime.h>
#include <hip/hip_bf16.h>
#include <math.h>

#define RR 21
#define HPX 64
#define WPX 64
#define IMGW 147
#define PI_F 3.14159265358979323846f
#define TWO_PI_F 6.28318530717958647692f
#define TAU_F 0.1f

__device__ __forceinline__ float mod2pi(float x) {
    float r = fmodf(x, TWO_PI_F);
    return r < 0.f ? r + TWO_PI_F : r;
}

// (dtheta/PI - 1)^35
__device__ __forceinline__ float gpow35(float dtheta) {
    float t = dtheta * (1.f / PI_F) - 1.f;
    float t2 = t * t;
    float t4 = t2 * t2;
    float t8 = t4 * t4;
    float t16 = t8 * t8;
    float t32 = t16 * t16;
    return t32 * t2 * t;
}

__global__ __launch_bounds__(256) void wedge_colors_kernel(
    const float* __restrict__ ests,   // (4096, 5)
    const float* __restrict__ img,    // (147, 147, 3) HWC
    float* __restrict__ out)          // (3, 3, 64, 64)  c,k,h,w
{
    const int wave = threadIdx.x >> 6;
    const int lane = threadIdx.x & 63;
    const int p = blockIdx.x * 4 + wave;      // pixel index 0..4095
    const int ph = p >> 6;
    const int pw = p & 63;

    // ---- per-pixel setup (redundant across lanes; cheap) ----
    const float* e = ests + p * 5;
    float b0 = mod2pi((e[0] + 1.f) * PI_F);
    float b1 = mod2pi((e[1] + 1.f) * PI_F);
    float b2 = mod2pi((e[2] + 1.f) * PI_F);
    float a1 = fminf(b0, fminf(b1, b2));
    float a3 = fmaxf(b0, fmaxf(b1, b2));
    float a2 = (b0 + b1 + b2) - a1 - a3;
    float x0 = e[3] * 3.f;
    float y0 = e[4] * 3.f;

    float mhalf = mod2pi(0.5f * (a1 - a3));
    float a4 = 0.5f * (a1 + a3) + (mhalf >= PI_F ? PI_F : 0.f);

    float d42 = mod2pi(a2 - a4);
    float d13 = mod2pi(a3 - a1);
    float sgn42 = (d42 < PI_F) ? 1.f : -1.f;
    float sgn13 = (d13 < PI_F) ? 1.f : -1.f;
    float g42 = gpow35(d42) * TAU_F;
    float g13 = gpow35(d13) * TAU_F;

    float s1, c1, s2, c2, s3, c3, s4, c4;
    sincosf(a1, &s1, &c1);
    sincosf(a2, &s2, &c2);
    sincosf(a3, &s3, &c3);
    sincosf(a4, &s4, &c4);

    // ---- accumulate over 21x21 samples ----
    float acc[12];
#pragma unroll
    for (int i = 0; i < 12; i++) acc[i] = 0.f;

    for (int idx = lane; idx < RR * RR; idx += 64) {
        int r = idx / RR;
        int s = idx - r * RR;
        float x = (float)s * 0.1f - 1.f;   // grid[s]
        float y = (float)r * 0.1f - 1.f;   // grid[r]
        float dx = x - x0;
        float dy = y - y0;

        float L1 = -s1 * dx + c1 * dy;
        float L2 = -s2 * dx + c2 * dy;
        float L3 = -s3 * dx + c3 * dy;
        float L4 = -s4 * dx + c4 * dy;

        float dist13 = sgn13 * fminf(sgn13 * L1, -sgn13 * L3) + g13;
        float dist42 = sgn42 * fminf(sgn42 * L4, -sgn42 * L2) + g42;

        // h = 0.5*(1 + 2/pi * atan(dist/eta)), eta=0.01
        float h0 = 0.5f + 0.318309886183790672f * atanf(dist13 * 100.f);
        float h1 = 0.5f + 0.318309886183790672f * atanf(dist42 * 100.f);

        float w0 = 1.f - h0;
        float w2 = h0 * h1;
        float w1 = h0 - w2;

        const float* px = img + ((ph * 2 + r) * IMGW + (pw * 2 + s)) * 3;
        float p0 = px[0];
        float p1 = px[1];
        float p2 = px[2];

        acc[0] += p0 * w0;  acc[1] += p0 * w1;  acc[2] += p0 * w2;
        acc[3] += p1 * w0;  acc[4] += p1 * w1;  acc[5] += p1 * w2;
        acc[6] += p2 * w0;  acc[7] += p2 * w1;  acc[8] += p2 * w2;
        acc[9] += w0;       acc[10] += w1;      acc[11] += w2;
    }

    // ---- wave butterfly reduction (64 lanes) ----
#pragma unroll
    for (int off = 32; off > 0; off >>= 1) {
#pragma unroll
        for (int i = 0; i < 12; i++) acc[i] += __shfl_xor(acc[i], off, 64);
    }

    if (lane == 0) {
        float inv0 = 1.f / (acc[9]  + 1e-10f);
        float inv1 = 1.f / (acc[10] + 1e-10f);
        float inv2 = 1.f / (acc[11] + 1e-10f);
        const int base = ph * WPX + pw;
        // out[((c*3 + k)*64 + ph)*64 + pw]
        out[0 * 4096 + base] = acc[0] * inv0;
        out[1 * 4096 + base] = acc[1] * inv1;
        out[2 * 4096 + base] = acc[2] * inv2;
        out[3 * 4096 + base] = acc[3] * inv0;
        out[4 * 4096 + base] = acc[4] * inv1;
        out[5 * 4096 + base] = acc[5] * inv2;
        out[6 * 4096 + base] = acc[6] * inv0;
        out[7 * 4096 + base] = acc[7] * inv1;
        out[8 * 4096 + base] = acc[8] * inv2;
    }
}

extern "C" void kernel_launch(void* const* d_in, const int* in_sizes, int n_in,
                              void* d_out, int out_size, void* d_ws, size_t ws_size,
                              hipStream_t stream) {
    const float* ests  = (const float*)d_in[0];   // (1, 4096, 5)
    const float* noisy = (const float*)d_in[1];   // (1, 147, 147, 3)
    // d_in[2] = gt_image (unused), d_in[3] = alpha (unused)
    float* out = (float*)d_out;                   // (1, 3, 3, 64, 64)

    wedge_colors_kernel<<<1024, 256, 0, stream>>>(ests, noisy, out);
}

// Round 2
// 65.103 us; speedup vs baseline: 1.0560x; 1.0560x over previous
//
#include <hip/hip_runtime.h>
#include <hip/hip_bf16.h>
#include <math.h>

#define HPX 64
#define WPX 64
#define IMGW 147
#define PI_F 3.14159265358979323846f
#define TWO_PI_F 6.28318530717958647692f
#define INV_TWO_PI_F 0.15915494309189533577f
#define INV_PI_F 0.31830988618379067154f
#define TAU_F 0.1f

// jnp.mod(x, 2pi) = x - floor(x/2pi)*2pi  (matches reference formula)
__device__ __forceinline__ float mod2pi(float x) {
    float t = floorf(x * INV_TWO_PI_F);
    return fmaf(-t, TWO_PI_F, x);
}

// (dtheta/PI - 1)^35
__device__ __forceinline__ float gpow35(float dtheta) {
    float t = dtheta * INV_PI_F - 1.f;
    float t2 = t * t;
    float t4 = t2 * t2;
    float t8 = t4 * t4;
    float t16 = t8 * t8;
    float t32 = t16 * t16;
    return t32 * t2 * t;
}

// h = 0.5 + atan(100*d)/pi   via degree-7 minimax atan on [0,1] + rcp fold.
// |atan err| <= ~1e-4 rad -> |h err| <= 3.2e-5 (threshold slack ~1.1e-2).
__device__ __forceinline__ float fast_h(float d) {
    float z = d * 100.f;
    float az = fabsf(z);
    bool big = az > 1.0f;
    float r = big ? __builtin_amdgcn_rcpf(az) : az;
    float a = r * r;
    float pol = r * fmaf(a, fmaf(a, fmaf(a, -0.0851330f, 0.1801410f), -0.3302995f),
                         0.9998660f);
    float res = big ? (1.5707963267948966f - pol) : pol;
    res = copysignf(res, z);
    return fmaf(res, INV_PI_F, 0.5f);
}

__global__ __launch_bounds__(256) void wedge_colors_kernel(
    const float* __restrict__ ests,   // (4096, 5)
    const float* __restrict__ img,    // (147, 147, 3) HWC
    float* __restrict__ out)          // (3, 3, 64, 64)
{
    const int wave = threadIdx.x >> 6;
    const int lane = threadIdx.x & 63;
    const int p = blockIdx.x * 4 + wave;      // pixel 0..4095
    const int ph = p >> 6;
    const int pw = p & 63;

    // ---- per-pixel setup (wave-uniform) ----
    const float* e = ests + p * 5;
    float b0 = mod2pi((e[0] + 1.f) * PI_F);
    float b1 = mod2pi((e[1] + 1.f) * PI_F);
    float b2 = mod2pi((e[2] + 1.f) * PI_F);
    float a1 = fminf(b0, fminf(b1, b2));
    float a3 = fmaxf(b0, fmaxf(b1, b2));
    float a2 = fmaxf(fminf(b0, b1), fminf(fmaxf(b0, b1), b2));  // exact median
    float x0 = e[3] * 3.f;
    float y0 = e[4] * 3.f;

    float mhalf = mod2pi(0.5f * (a1 - a3));
    float a4 = 0.5f * (a1 + a3) + (mhalf >= PI_F ? PI_F : 0.f);

    float d42m = mod2pi(a2 - a4);
    float d13m = mod2pi(a3 - a1);
    float sgn42 = (d42m < PI_F) ? 1.f : -1.f;
    float sgn13 = (d13m < PI_F) ? 1.f : -1.f;
    float g42 = gpow35(d42m) * TAU_F;
    float g13 = gpow35(d13m) * TAU_F;

    // v_sin/v_cos (input scaled to revolutions inside __sinf); err ~1e-6, fine.
    float s1 = __sinf(a1), c1 = __cosf(a1);
    float s2 = __sinf(a2), c2 = __cosf(a2);
    float s3 = __sinf(a3), c3 = __cosf(a3);
    float s4 = __sinf(a4), c4 = __cosf(a4);

    // ---- per-lane invariants: lane -> (row_off = lane/21, col = lane%21) ----
    // 63 lanes x 7 row-triples = 441 samples; lane 63 idle.
    const int r_off = lane / 21;                  // 0..3 (3 for lane 63)
    const int s     = lane - 21 * r_off;          // 0..20
    float x  = (float)s * 0.1f - 1.f;
    float dx = x - x0;

    // sign-folded line coefficients:
    //  t1 =  sgn13*L1 = fma(P1, dy, B1)   t3 = -sgn13*L3 = fma(P3, dy, B3)
    //  t4 =  sgn42*L4 = fma(P4, dy, B4)   t2 = -sgn42*L2 = fma(P2, dy, B2)
    float P1 =  sgn13 * c1, B1 = -sgn13 * s1 * dx;
    float P3 = -sgn13 * c3, B3 =  sgn13 * s3 * dx;
    float P4 =  sgn42 * c4, B4 = -sgn42 * s4 * dx;
    float P2 = -sgn42 * c2, B2 =  sgn42 * s2 * dx;

    // 11 accumulators: sum(p), sum(p*h0), sum(p*h0*h1), sum(h0), sum(h0*h1)
    float sp0 = 0.f, sp1 = 0.f, sp2 = 0.f;
    float sa0 = 0.f, sa1 = 0.f, sa2 = 0.f;
    float sb0 = 0.f, sb1 = 0.f, sb2 = 0.f;
    float sh = 0.f, su = 0.f;

    if (lane < 63) {
        const float* base = img + ((2 * ph + r_off) * IMGW + (2 * pw + s)) * 3;
#pragma unroll
        for (int k = 0; k < 7; k++) {
            int r = r_off + 3 * k;
            float y  = (float)r * 0.1f - 1.f;
            float dy = y - y0;

            const float* px = base + k * (3 * IMGW * 3);   // += 3 rows
            float p0 = px[0];
            float p1 = px[1];
            float p2 = px[2];

            float t1 = fmaf(P1, dy, B1);
            float t3 = fmaf(P3, dy, B3);
            float t4 = fmaf(P4, dy, B4);
            float t2 = fmaf(P2, dy, B2);

            float d13 = fmaf(sgn13, fminf(t1, t3), g13);
            float d42 = fmaf(sgn42, fminf(t4, t2), g42);

            float h0 = fast_h(d13);
            float h1 = fast_h(d42);
            float u  = h0 * h1;

            sp0 += p0;            sp1 += p1;            sp2 += p2;
            sa0 = fmaf(p0, h0, sa0); sa1 = fmaf(p1, h0, sa1); sa2 = fmaf(p2, h0, sa2);
            sb0 = fmaf(p0, u, sb0);  sb1 = fmaf(p1, u, sb1);  sb2 = fmaf(p2, u, sb2);
            sh += h0;             su += u;
        }
    }

    // ---- wave butterfly reduction over 64 lanes (lane63 contributes zeros) ----
#pragma unroll
    for (int off = 32; off > 0; off >>= 1) {
        sp0 += __shfl_xor(sp0, off, 64); sp1 += __shfl_xor(sp1, off, 64); sp2 += __shfl_xor(sp2, off, 64);
        sa0 += __shfl_xor(sa0, off, 64); sa1 += __shfl_xor(sa1, off, 64); sa2 += __shfl_xor(sa2, off, 64);
        sb0 += __shfl_xor(sb0, off, 64); sb1 += __shfl_xor(sb1, off, 64); sb2 += __shfl_xor(sb2, off, 64);
        sh  += __shfl_xor(sh,  off, 64); su  += __shfl_xor(su,  off, 64);
    }

    if (lane == 0) {
        // wsum: w0 = 441 - sum(h0), w1 = sum(h0) - sum(h0h1), w2 = sum(h0h1)
        float inv0 = 1.f / (441.f - sh + 1e-10f);
        float inv1 = 1.f / (sh - su + 1e-10f);
        float inv2 = 1.f / (su + 1e-10f);
        const int base = ph * WPX + pw;
        out[0 * 4096 + base] = (sp0 - sa0) * inv0;
        out[1 * 4096 + base] = (sa0 - sb0) * inv1;
        out[2 * 4096 + base] = sb0 * inv2;
        out[3 * 4096 + base] = (sp1 - sa1) * inv0;
        out[4 * 4096 + base] = (sa1 - sb1) * inv1;
        out[5 * 4096 + base] = sb1 * inv2;
        out[6 * 4096 + base] = (sp2 - sa2) * inv0;
        out[7 * 4096 + base] = (sa2 - sb2) * inv1;
        out[8 * 4096 + base] = sb2 * inv2;
    }
}

extern "C" void kernel_launch(void* const* d_in, const int* in_sizes, int n_in,
                              void* d_out, int out_size, void* d_ws, size_t ws_size,
                              hipStream_t stream) {
    const float* ests  = (const float*)d_in[0];   // (1, 4096, 5)
    const float* noisy = (const float*)d_in[1];   // (1, 147, 147, 3)
    float* out = (float*)d_out;                   // (1, 3, 3, 64, 64)

    wedge_colors_kernel<<<1024, 256, 0, stream>>>(ests, noisy, out);
}